// Round 6
// baseline (518.185 us; speedup 1.0000x reference)
//
#include <hip/hip_runtime.h>
#include <math.h>

#define KK 128
#define TT 512
#define BB 512
#define TAG_START 126
#define TAG_STOP 127

typedef float v4f __attribute__((ext_vector_type(4)));

// padded x index: quarter q (rows 32q..32q+31) starts at float 40q -> quarter
// bases hit banks {0,8,16,24}: 4 distinct b128 addrs/wave are bank-disjoint.
#define XIDX(r) ((r) + (((r) >> 5) << 3))

// ws layout (floats): fwd [0,512), gold [512,1024)

// Blocks 0..255: forward recursion for sequence PAIR (2b, 2b+1) — one block
//   per CU, ONE round: kills the multi-round length-imbalance tail of R5.
//   512 threads = 8 waves. wave w, lane l: row = 16w + (l&15), kq = l>>4.
//   Thread holds E[row][32kq..+32) in 32 regs (volatile-asm pinned, AGPR-side).
//   Hot path (t < min len): both seqs' dots straight-line interleaved (ILP);
//   tail: single-seq. Intra-wave K-reduce (shfl 16,32); ONE barrier/step;
//   xs double-buffered; em prefetch depth 4 per seq.
// Blocks 256..511: gold scores for pair (2g, 2g+1), half-block each.
__global__ __launch_bounds__(512, 2) void fused_kernel(
    const float* __restrict__ feats, const float* __restrict__ trans,
    const int* __restrict__ tags, const int* __restrict__ lengths,
    float* __restrict__ fwd_out, float* __restrict__ gold_out) {
    int tid = threadIdx.x;

    if (blockIdx.x < BB / 2) {
        // ---------------- forward path: pair (b0, b1) ----------------
        int b0 = 2 * blockIdx.x, b1 = b0 + 1;
        int w = tid >> 6;
        int l = tid & 63;
        int row = 16 * w + (l & 15);
        int kq = l >> 4;

        __shared__ __align__(16) float xs[2][2][160];  // [parity][seq][padded k]
        __shared__ float As[2][2];                     // [seq][parity]
        __shared__ float redm[2][8], reds[2][8];

        // --- pin E quarter-row (32 floats) via volatile asm loads ---
        const float* tp = trans + row * KK + 32 * kq;
        v4f tv[8];
#pragma unroll
        for (int q = 0; q < 8; q++) {
            asm volatile("global_load_dwordx4 %0, %1, off"
                         : "=v"(tv[q]) : "v"(tp + 4 * q));
        }
        int len0 = lengths[b0], len1 = lengths[b1];
        const float* fbr0 = feats + (size_t)b0 * TT * KK + row;
        const float* fbr1 = feats + (size_t)b1 * TT * KK + row;
        asm volatile("s_waitcnt vmcnt(0)"
                     : "+v"(tv[0]), "+v"(tv[1]), "+v"(tv[2]), "+v"(tv[3]),
                       "+v"(tv[4]), "+v"(tv[5]), "+v"(tv[6]), "+v"(tv[7]));

        float m32 = -1e30f;
#pragma unroll
        for (int q = 0; q < 8; q++)
            m32 = fmaxf(m32, fmaxf(fmaxf(tv[q].x, tv[q].y), fmaxf(tv[q].z, tv[q].w)));
        m32 = fmaxf(m32, __shfl_xor(m32, 16));
        float Mj = fmaxf(m32, __shfl_xor(m32, 32));

        float Erow[32];
#pragma unroll
        for (int q = 0; q < 8; q++) {
            Erow[4 * q + 0] = __expf(tv[q].x - Mj);
            Erow[4 * q + 1] = __expf(tv[q].y - Mj);
            Erow[4 * q + 2] = __expf(tv[q].z - Mj);
            Erow[4 * q + 3] = __expf(tv[q].w - Mj);
        }

        if (l < 16) {
            float x0 = (row == TAG_START) ? 1.0f : 0.0f;
            xs[0][0][XIDX(row)] = x0;
            xs[0][1][XIDX(row)] = x0;
        }
        if (tid == 0) { As[0][0] = As[0][1] = As[1][0] = As[1][1] = 0.f; }

        float alpha0 = 0.f, A0 = 0.f, alpha1 = 0.f, A1 = 0.f;
        float emb0[4], emb1[4];
#pragma unroll
        for (int d = 0; d < 4; d++) {
            emb0[d] = fbr0[(size_t)((d < len0) ? d : (len0 - 1)) * KK];
            emb1[d] = fbr1[(size_t)((d < len1) ? d : (len1 - 1)) * KK];
        }
        __syncthreads();

        int lenmin = min(len0, len1), lenmax = max(len0, len1);
        int tmax = (lenmax + 3) & ~3;
        for (int t0 = 0; t0 < tmax; t0 += 4) {
#pragma unroll
            for (int d = 0; d < 4; d++) {
                int t = t0 + d;
                if (t < lenmin) {
                    // ---- hot path: both sequences, interleaved ----
                    float em0 = emb0[d], em1 = emb1[d];
                    int tf0 = (t + 4 < len0) ? (t + 4) : (len0 - 1);
                    int tf1 = (t + 4 < len1) ? (t + 4) : (len1 - 1);
                    emb0[d] = fbr0[(size_t)tf0 * KK];
                    emb1[d] = fbr1[(size_t)tf1 * KK];
                    int cur = t & 1, nxt = cur ^ 1;
                    float Sn0 = As[0][nxt], Sn1 = As[1][nxt];
                    const v4f* x40 = (const v4f*)(xs[cur][0] + 40 * kq);
                    const v4f* x41 = (const v4f*)(xs[cur][1] + 40 * kq);
                    float s00 = 0.f, s01 = 0.f, s02 = 0.f, s03 = 0.f;
                    float s10 = 0.f, s11 = 0.f, s12 = 0.f, s13 = 0.f;
#pragma unroll
                    for (int q = 0; q < 8; q++) {
                        v4f xv0 = x40[q], xv1 = x41[q];
                        s00 = fmaf(Erow[4 * q + 0], xv0.x, s00);
                        s10 = fmaf(Erow[4 * q + 0], xv1.x, s10);
                        s01 = fmaf(Erow[4 * q + 1], xv0.y, s01);
                        s11 = fmaf(Erow[4 * q + 1], xv1.y, s11);
                        s02 = fmaf(Erow[4 * q + 2], xv0.z, s02);
                        s12 = fmaf(Erow[4 * q + 2], xv1.z, s12);
                        s03 = fmaf(Erow[4 * q + 3], xv0.w, s03);
                        s13 = fmaf(Erow[4 * q + 3], xv1.w, s13);
                    }
                    float y0 = (s00 + s01) + (s02 + s03);
                    float y1 = (s10 + s11) + (s12 + s13);
                    y0 += __shfl_xor(y0, 16);
                    y1 += __shfl_xor(y1, 16);
                    y0 += __shfl_xor(y0, 32);
                    y1 += __shfl_xor(y1, 32);
                    alpha0 = em0 + Mj + A0 + __logf(y0);
                    alpha1 = em1 + Mj + A1 + __logf(y1);
                    if (l < 16) {
                        xs[nxt][0][XIDX(row)] = __expf(alpha0 - Sn0);
                        xs[nxt][1][XIDX(row)] = __expf(alpha1 - Sn1);
                    }
                    if (tid == 0) { As[0][cur] = alpha0; As[1][cur] = alpha1; }
                    A0 = Sn0;
                    A1 = Sn1;
                    __syncthreads();
                } else if (t < lenmax) {
                    // ---- tail: at most one sequence still active ----
                    if (t < len0) {
                        float em0 = emb0[d];
                        int tf0 = (t + 4 < len0) ? (t + 4) : (len0 - 1);
                        emb0[d] = fbr0[(size_t)tf0 * KK];
                        int cur = t & 1, nxt = cur ^ 1;
                        float Sn0 = As[0][nxt];
                        const v4f* x40 = (const v4f*)(xs[cur][0] + 40 * kq);
                        float s00 = 0.f, s01 = 0.f, s02 = 0.f, s03 = 0.f;
#pragma unroll
                        for (int q = 0; q < 8; q++) {
                            v4f xv0 = x40[q];
                            s00 = fmaf(Erow[4 * q + 0], xv0.x, s00);
                            s01 = fmaf(Erow[4 * q + 1], xv0.y, s01);
                            s02 = fmaf(Erow[4 * q + 2], xv0.z, s02);
                            s03 = fmaf(Erow[4 * q + 3], xv0.w, s03);
                        }
                        float y0 = (s00 + s01) + (s02 + s03);
                        y0 += __shfl_xor(y0, 16);
                        y0 += __shfl_xor(y0, 32);
                        alpha0 = em0 + Mj + A0 + __logf(y0);
                        if (l < 16) xs[nxt][0][XIDX(row)] = __expf(alpha0 - Sn0);
                        if (tid == 0) As[0][cur] = alpha0;
                        A0 = Sn0;
                    }
                    if (t < len1) {
                        float em1 = emb1[d];
                        int tf1 = (t + 4 < len1) ? (t + 4) : (len1 - 1);
                        emb1[d] = fbr1[(size_t)tf1 * KK];
                        int cur = t & 1, nxt = cur ^ 1;
                        float Sn1 = As[1][nxt];
                        const v4f* x41 = (const v4f*)(xs[cur][1] + 40 * kq);
                        float s10 = 0.f, s11 = 0.f, s12 = 0.f, s13 = 0.f;
#pragma unroll
                        for (int q = 0; q < 8; q++) {
                            v4f xv1 = x41[q];
                            s10 = fmaf(Erow[4 * q + 0], xv1.x, s10);
                            s11 = fmaf(Erow[4 * q + 1], xv1.y, s11);
                            s12 = fmaf(Erow[4 * q + 2], xv1.z, s12);
                            s13 = fmaf(Erow[4 * q + 3], xv1.w, s13);
                        }
                        float y1 = (s10 + s11) + (s12 + s13);
                        y1 += __shfl_xor(y1, 16);
                        y1 += __shfl_xor(y1, 32);
                        alpha1 = em1 + Mj + A1 + __logf(y1);
                        if (l < 16) xs[nxt][1][XIDX(row)] = __expf(alpha1 - Sn1);
                        if (tid == 0) As[1][cur] = alpha1;
                        A1 = Sn1;
                    }
                    __syncthreads();
                }
            }
        }

        // terminal logsumexp for both seqs; lanes l<16 hold unique rows
        float tstop = trans[TAG_STOP * KK + row];
        float term0 = (l < 16) ? (alpha0 + tstop) : -1e30f;
        float term1 = (l < 16) ? (alpha1 + tstop) : -1e30f;
        float m0 = term0, m1 = term1;
#pragma unroll
        for (int off = 8; off >= 1; off >>= 1) {
            m0 = fmaxf(m0, __shfl_xor(m0, off));
            m1 = fmaxf(m1, __shfl_xor(m1, off));
        }
        m0 = fmaxf(m0, __shfl_xor(m0, 16));
        m1 = fmaxf(m1, __shfl_xor(m1, 16));
        m0 = fmaxf(m0, __shfl_xor(m0, 32));
        m1 = fmaxf(m1, __shfl_xor(m1, 32));
        float s0 = (l < 16) ? __expf(term0 - m0) : 0.f;
        float s1 = (l < 16) ? __expf(term1 - m1) : 0.f;
#pragma unroll
        for (int off = 8; off >= 1; off >>= 1) {
            s0 += __shfl_xor(s0, off);
            s1 += __shfl_xor(s1, off);
        }
        s0 += __shfl_xor(s0, 16);
        s1 += __shfl_xor(s1, 16);
        s0 += __shfl_xor(s0, 32);
        s1 += __shfl_xor(s1, 32);
        if (l == 0) { redm[0][w] = m0; reds[0][w] = s0; redm[1][w] = m1; reds[1][w] = s1; }
        __syncthreads();
        if (tid == 0) {
#pragma unroll
            for (int s = 0; s < 2; s++) {
                float M2 = redm[s][0];
                for (int i = 1; i < 8; i++) M2 = fmaxf(M2, redm[s][i]);
                float S2 = 0.f;
                for (int i = 0; i < 8; i++) S2 += reds[s][i] * __expf(redm[s][i] - M2);
                fwd_out[b0 + s] = M2 + __logf(S2);
            }
        }
    } else {
        // ---------------- gold path: pair (b0, b1), half-block each ----------------
        int g = blockIdx.x - BB / 2;
        int b0 = 2 * g;
        int s = tid >> 8;          // 0: seq b0 (waves 0-3), 1: seq b1 (waves 4-7)
        int t2 = tid & 255;
        int b = b0 + s;
        int len = lengths[b];
        const int* tg = tags + (size_t)b * TT;
        const float* fb = feats + (size_t)b * TT * KK;
        float acc = 0.f;
        for (int i = t2; i <= len; i += 256) {
            int from = (i == 0) ? TAG_START : tg[i - 1];
            int to = (i < len) ? tg[i] : TAG_STOP;
            acc += trans[to * KK + from];
        }
        for (int t = t2; t < len; t += 256)
            acc += fb[(size_t)t * KK + tg[t]];
        __shared__ float sred[8];
#pragma unroll
        for (int off = 32; off >= 1; off >>= 1) acc += __shfl_xor(acc, off);
        if ((tid & 63) == 0) sred[tid >> 6] = acc;
        __syncthreads();
        if (tid == 0) {
            gold_out[b0] = (sred[0] + sred[1]) + (sred[2] + sred[3]);
            gold_out[b0 + 1] = (sred[4] + sred[5]) + (sred[6] + sred[7]);
        }
    }
}

__global__ __launch_bounds__(512) void final_kernel(const float* __restrict__ fwd_s,
                                                    const float* __restrict__ gold_s,
                                                    float* __restrict__ out) {
    int tid = threadIdx.x;
    float v = fabsf(fwd_s[tid] - gold_s[tid]);
#pragma unroll
    for (int off = 32; off >= 1; off >>= 1) v += __shfl_xor(v, off);
    __shared__ float sred[8];
    if ((tid & 63) == 0) sred[tid >> 6] = v;
    __syncthreads();
    if (tid == 0) {
        float s = 0.f;
        for (int i = 0; i < 8; i++) s += sred[i];
        out[0] = s / (float)BB;
    }
}

extern "C" void kernel_launch(void* const* d_in, const int* in_sizes, int n_in,
                              void* d_out, int out_size, void* d_ws, size_t ws_size,
                              hipStream_t stream) {
    const float* feats = (const float*)d_in[0];
    const float* trans = (const float*)d_in[1];
    const int* tags = (const int*)d_in[2];
    const int* lengths = (const int*)d_in[3];

    float* ws = (float*)d_ws;
    float* fwdv = ws;
    float* goldv = ws + BB;

    fused_kernel<<<BB, 512, 0, stream>>>(feats, trans, tags, lengths, fwdv, goldv);
    final_kernel<<<1, 512, 0, stream>>>(fwdv, goldv, (float*)d_out);
}

// Round 7
// 362.259 us; speedup vs baseline: 1.4304x; 1.4304x over previous
//
#include <hip/hip_runtime.h>
#include <math.h>

#define KK 128
#define TT 512
#define BB 512
#define TAG_START 126
#define TAG_STOP 127

typedef float v4f __attribute__((ext_vector_type(4)));

// padded x index: quarter q (rows 32q..32q+31) starts at float 40q -> quarter
// bases hit banks {0,8,16,24}: 4 distinct b128 addrs/wave are bank-disjoint.
#define XIDX(r) ((r) + (((r) >> 5) << 3))

// quad_perm DPP add: xor1 = 0xB1 [1,0,3,2], xor2 = 0x4E [2,3,0,1]
__device__ __forceinline__ float quad_add(float x, int ctrl) {
    int yi;
    if (ctrl == 0xB1)
        yi = __builtin_amdgcn_update_dpp(0, __float_as_int(x), 0xB1, 0xF, 0xF, true);
    else
        yi = __builtin_amdgcn_update_dpp(0, __float_as_int(x), 0x4E, 0xF, 0xF, true);
    return x + __int_as_float(yi);
}

// ws layout: floats fwd [0,512), gold [512,1024); ints order [1024,1536)

// Descending-length rank (LPT schedule): order[r] = seq index with rank r.
__global__ __launch_bounds__(512) void order_kernel(const int* __restrict__ lengths,
                                                    int* __restrict__ order) {
    __shared__ int L[BB];
    int tid = threadIdx.x;
    L[tid] = lengths[tid];
    __syncthreads();
    int mylen = L[tid];
    int r = 0;
    for (int i = 0; i < BB; i++) {
        int li = L[i];
        r += (li > mylen) || (li == mylen && i < tid);
    }
    order[r] = tid;
}

// Blocks 0..511: forward recursion for seq b = order[blockIdx.x] (longest first).
//   512 threads = 8 waves. wave w, lane l: kq = l&3, row = 16w + (l>>2).
//   Thread holds E[row][32kq..+32) in 32 regs (volatile-asm pinned, AGPR-side).
//   K-reduce = 2 DPP quad_perm adds (VALU, ~10cy — replaces ds_permute shfls).
//   x-write chain is y*fac with fac=exp(em+Mj+A-Sn) precomputed in dot shadow;
//   log only feeds As/terminal (off-chain). ONE barrier/step; xs dbuf; em
//   prefetch depth 8.
// Blocks 512..1023: gold score for seq b-512.
__global__ __launch_bounds__(512, 4) void fused_kernel(
    const float* __restrict__ feats, const float* __restrict__ trans,
    const int* __restrict__ tags, const int* __restrict__ lengths,
    const int* __restrict__ order,
    float* __restrict__ fwd_out, float* __restrict__ gold_out) {
    int tid = threadIdx.x;

    if (blockIdx.x < BB) {
        // ---------------- forward path ----------------
        int b = order[blockIdx.x];
        int w = tid >> 6;
        int l = tid & 63;
        int kq = l & 3;
        int row = 16 * w + (l >> 2);

        __shared__ __align__(16) float xs[2][160];   // padded (XIDX)
        __shared__ float As[2];
        __shared__ float redm[8], reds[8];

        // --- pin E quarter-row (32 floats) via volatile asm loads ---
        const float* tp = trans + row * KK + 32 * kq;
        v4f tv[8];
#pragma unroll
        for (int q = 0; q < 8; q++) {
            asm volatile("global_load_dwordx4 %0, %1, off"
                         : "=v"(tv[q]) : "v"(tp + 4 * q));
        }
        int len = lengths[b];
        const float* fbr = feats + (size_t)b * TT * KK + row;
        asm volatile("s_waitcnt vmcnt(0)"
                     : "+v"(tv[0]), "+v"(tv[1]), "+v"(tv[2]), "+v"(tv[3]),
                       "+v"(tv[4]), "+v"(tv[5]), "+v"(tv[6]), "+v"(tv[7]));

        // full-row max: 32-local -> quad reduce (kq partners are quad lanes)
        float m32 = -1e30f;
#pragma unroll
        for (int q = 0; q < 8; q++)
            m32 = fmaxf(m32, fmaxf(fmaxf(tv[q].x, tv[q].y), fmaxf(tv[q].z, tv[q].w)));
        m32 = fmaxf(m32, __shfl_xor(m32, 1));
        float Mj = fmaxf(m32, __shfl_xor(m32, 2));

        float Erow[32];
#pragma unroll
        for (int q = 0; q < 8; q++) {
            Erow[4 * q + 0] = __expf(tv[q].x - Mj);
            Erow[4 * q + 1] = __expf(tv[q].y - Mj);
            Erow[4 * q + 2] = __expf(tv[q].z - Mj);
            Erow[4 * q + 3] = __expf(tv[q].w - Mj);
        }

        // init x(0) = exp(alpha0 - 0); one writer per row (quad lane 0)
        if (kq == 0) xs[0][XIDX(row)] = (row == TAG_START) ? 1.0f : 0.0f;
        if (tid == 0) { As[0] = 0.f; As[1] = 0.f; }

        float alpha = 0.f, A = 0.f;
        // rolling 8-deep emission prefetch (hides ~900cy HBM miss latency)
        float emb[8];
#pragma unroll
        for (int d = 0; d < 8; d++) {
            int tf = (d < len) ? d : (len - 1);
            emb[d] = fbr[(size_t)tf * KK];
        }
        __syncthreads();

        int tmax = (len + 7) & ~7;
        for (int t0 = 0; t0 < tmax; t0 += 8) {
#pragma unroll
            for (int d = 0; d < 8; d++) {
                int t = t0 + d;
                if (t < len) {                       // block-uniform guard
                    float em = emb[d];
                    int tf = (t + 8 < len) ? (t + 8) : (len - 1);
                    emb[d] = fbr[(size_t)tf * KK];   // issue 8 steps ahead

                    int cur = t & 1, nxt = cur ^ 1;
                    float Sn = As[nxt];              // alpha_0(t-1): shift of x(t+1)
                    float fac = __expf(em + Mj + A - Sn);  // off-chain, in dot shadow
                    const v4f* x4 = (const v4f*)(xs[cur] + 40 * kq);
                    float s0 = 0.f, s1 = 0.f, s2 = 0.f, s3 = 0.f;
#pragma unroll
                    for (int q = 0; q < 8; q++) {
                        v4f xv = x4[q];              // broadcast, bank-disjoint
                        s0 = fmaf(Erow[4 * q + 0], xv.x, s0);
                        s1 = fmaf(Erow[4 * q + 1], xv.y, s1);
                        s2 = fmaf(Erow[4 * q + 2], xv.z, s2);
                        s3 = fmaf(Erow[4 * q + 3], xv.w, s3);
                    }
                    float yq = (s0 + s1) + (s2 + s3);
                    yq = quad_add(yq, 0xB1);         // xor1 (DPP)
                    float y = quad_add(yq, 0x4E);    // xor2 (DPP) -> full row sum
                    if (kq == 0) xs[nxt][XIDX(row)] = y * fac;  // = exp(alpha - Sn)
                    alpha = em + Mj + A + __logf(y); // off-chain: As/terminal only
                    if (tid == 0) As[cur] = alpha;   // shift used at step t+1
                    A = Sn;
                    __syncthreads();                 // single barrier per step
                }
            }
        }

        // terminal logsumexp_j( alpha[j] + trans[STOP,j] ); quad lane 0 unique
        float term = (kq == 0) ? (alpha + trans[TAG_STOP * KK + row]) : -1e30f;
        float m = term;
#pragma unroll
        for (int off = 32; off >= 1; off >>= 1) m = fmaxf(m, __shfl_xor(m, off));
        float s = (kq == 0) ? __expf(term - m) : 0.f;
#pragma unroll
        for (int off = 32; off >= 1; off >>= 1) s += __shfl_xor(s, off);
        if (l == 0) { redm[w] = m; reds[w] = s; }
        __syncthreads();
        if (tid == 0) {
            float M2 = redm[0];
            for (int i = 1; i < 8; i++) M2 = fmaxf(M2, redm[i]);
            float S2 = 0.f;
            for (int i = 0; i < 8; i++) S2 += reds[i] * __expf(redm[i] - M2);
            fwd_out[b] = M2 + __logf(S2);
        }
    } else {
        // ---------------- gold path ----------------
        int b = blockIdx.x - BB;
        int len = lengths[b];
        const int* tg = tags + (size_t)b * TT;
        const float* fb = feats + (size_t)b * TT * KK;
        float acc = 0.f;
        for (int i = tid; i <= len; i += 512) {
            int from = (i == 0) ? TAG_START : tg[i - 1];
            int to = (i < len) ? tg[i] : TAG_STOP;
            acc += trans[to * KK + from];
        }
        for (int t = tid; t < len; t += 512)
            acc += fb[(size_t)t * KK + tg[t]];
        __shared__ float sred[8];
#pragma unroll
        for (int off = 32; off >= 1; off >>= 1) acc += __shfl_xor(acc, off);
        if ((tid & 63) == 0) sred[tid >> 6] = acc;
        __syncthreads();
        if (tid == 0) {
            float s = 0.f;
            for (int i = 0; i < 8; i++) s += sred[i];
            gold_out[b] = s;
        }
    }
}

__global__ __launch_bounds__(512) void final_kernel(const float* __restrict__ fwd_s,
                                                    const float* __restrict__ gold_s,
                                                    float* __restrict__ out) {
    int tid = threadIdx.x;
    float v = fabsf(fwd_s[tid] - gold_s[tid]);
#pragma unroll
    for (int off = 32; off >= 1; off >>= 1) v += __shfl_xor(v, off);
    __shared__ float sred[8];
    if ((tid & 63) == 0) sred[tid >> 6] = v;
    __syncthreads();
    if (tid == 0) {
        float s = 0.f;
        for (int i = 0; i < 8; i++) s += sred[i];
        out[0] = s / (float)BB;
    }
}

extern "C" void kernel_launch(void* const* d_in, const int* in_sizes, int n_in,
                              void* d_out, int out_size, void* d_ws, size_t ws_size,
                              hipStream_t stream) {
    const float* feats = (const float*)d_in[0];
    const float* trans = (const float*)d_in[1];
    const int* tags = (const int*)d_in[2];
    const int* lengths = (const int*)d_in[3];

    float* ws = (float*)d_ws;
    float* fwdv = ws;
    float* goldv = ws + BB;
    int* order = (int*)(ws + 2 * BB);

    order_kernel<<<1, 512, 0, stream>>>(lengths, order);
    fused_kernel<<<2 * BB, 512, 0, stream>>>(feats, trans, tags, lengths, order,
                                             fwdv, goldv);
    final_kernel<<<1, 512, 0, stream>>>(fwdv, goldv, (float*)d_out);
}